// Round 13
// baseline (677.581 us; speedup 1.0000x reference)
//
#include <hip/hip_runtime.h>
#include <hip/hip_bf16.h>

#define NH 64
#define NRELS 9
#define NEDGE 300000
#define NGRAPH 64
#define TOTROWS 250000
#define TOTSEG 660000
#define TOTEDGE (NRELS * NEDGE)
#define NBUCK 2583           // sum over r of ceil(Nd_r/256)
#define CHUNK 4096           // edges per block in binning passes (grid 660 blocks)
#define NBLK ((TOTEDGE + CHUNK - 1) / CHUNK)   // 660
#define KCH 20               // scan chunks over NBLK (33 blocks each)
#define KSP 33               // NBLK rows per scan chunk

typedef __attribute__((ext_vector_type(8))) short short8;
typedef __attribute__((ext_vector_type(4))) float f32x4;

__constant__ int c_NS[4]     = {100000, 20000, 50000, 80000};
__constant__ int c_SRC[9]    = {0,0,0,2,3,1,2,3,3};
__constant__ int c_DST[9]    = {1,2,3,3,3,0,0,0,2};
__constant__ int c_XOFF[5]   = {0,100000,120000,170000,250000};
__constant__ int c_ASOFF[10] = {0,100000,200000,300000,350000,430000,450000,500000,580000,660000};
__constant__ int c_ADOFF[10] = {0,20000,70000,150000,230000,310000,410000,510000,610000,660000};
__constant__ int c_BOFF[9]   = {0,79,275,588,901,1214,1605,1996,2387};  // bucket base per relation

struct EdgePtrs { const int* s[9]; const int* d[9]; };

__device__ __forceinline__ unsigned short f2bf(float f) {
  union { __hip_bfloat16 h; unsigned short u; } c;
  c.h = __float2bfloat16(f);
  return c.u;
}

// ---------------- setup: wv_s/wv_d = W @ a  (per l,r,side), bias presums ----------------
__global__ void k_setup(const float* Wsrc, const float* Wdst, const float* asrc,
                        const float* adst, const float* bias, float* wv, float* bsum) {
  int b = blockIdx.x, j = threadIdx.x;
  if (b < 36) {
    int r = b % 9, q = b / 9;
    int l = q >> 1, side = q & 1;
    const float* W = (side ? Wdst : Wsrc) + (l * 9 + r) * 64 * 64;
    const float* a = (side ? adst : asrc) + (l * 9 + r) * 64;
    float s = 0.f;
    for (int i = 0; i < 64; ++i) s += W[j * 64 + i] * a[i];
    wv[(side ? 1152 : 0) + (l * 9 + r) * 64 + j] = s;
  } else {
    for (int l = 0; l < 2; ++l)
      for (int t = 0; t < 4; ++t) {
        float s = 0.f;
        for (int r = 0; r < 9; ++r)
          if (c_DST[r] == t) s += bias[(l * 9 + r) * 64 + j];
        bsum[(l * 4 + t) * 64 + j] = s;
      }
  }
}

// ---------------- CSR build: deterministic block-private bucket sort (no global atomics) ----
__global__ __launch_bounds__(256) void k_bhist2(EdgePtrs Eg, int* bh) {
  __shared__ int sh[NBUCK];
  for (int i = threadIdx.x; i < NBUCK; i += 256) sh[i] = 0;
  __syncthreads();
  int lo = blockIdx.x * CHUNK;
  int hi = lo + CHUNK; if (hi > TOTEDGE) hi = TOTEDGE;
  for (int gid = lo + threadIdx.x; gid < hi; gid += 256) {
    int r = gid / NEDGE, e = gid - r * NEDGE;
    int d = Eg.d[r][e];
    atomicAdd(&sh[c_BOFF[r] + (d >> 8)], 1);
  }
  __syncthreads();
  int* dst = bh + (size_t)blockIdx.x * NBUCK;
  for (int i = threadIdx.x; i < NBUCK; i += 256) dst[i] = sh[i];
}

// 3-phase column scan
__global__ void k_cs1(const int* bh, int* csum) {
  int blk = blockIdx.x;               // 0..KCH*11-1
  int c = blk / 11;
  int b = (blk % 11) * 256 + threadIdx.x;
  if (b >= NBUCK) return;
  int k0 = c * KSP;
  int k1 = k0 + KSP; if (k1 > NBLK) k1 = NBLK;
  int s = 0;
  for (int k = k0; k < k1; ++k) s += bh[(size_t)k * NBUCK + b];
  csum[(size_t)c * NBUCK + b] = s;
}

__global__ void k_cs2(int* csum, int* gbh) {
  int b = blockIdx.x * 256 + threadIdx.x;
  if (b >= NBUCK) return;
  int run = 0;
#pragma unroll
  for (int c = 0; c < KCH; ++c) {
    size_t idx = (size_t)c * NBUCK + b;
    int t = csum[idx];
    csum[idx] = run;
    run += t;
  }
  gbh[b] = run;
}

__global__ void k_cs3(int* bh, const int* csum) {
  int blk = blockIdx.x;
  int c = blk / 11;
  int b = (blk % 11) * 256 + threadIdx.x;
  if (b >= NBUCK) return;
  int k0 = c * KSP;
  int k1 = k0 + KSP; if (k1 > NBLK) k1 = NBLK;
  int run = csum[(size_t)c * NBUCK + b];
  for (int k = k0; k < k1; ++k) {
    size_t idx = (size_t)k * NBUCK + b;
    int t = bh[idx];
    bh[idx] = run;
    run += t;
  }
}

__global__ void k_bscan(const int* gbh, int* boff) {
  __shared__ int sd[1024];
  int t = threadIdx.x;
  int v[3]; int s = 0;
#pragma unroll
  for (int k = 0; k < 3; ++k) { int i = t * 3 + k; v[k] = (i < NBUCK) ? gbh[i] : 0; s += v[k]; }
  sd[t] = s; __syncthreads();
  for (int o = 1; o < 1024; o <<= 1) {
    int x = (t >= o) ? sd[t - o] : 0; __syncthreads();
    sd[t] += x; __syncthreads();
  }
  int pre = sd[t] - s;
#pragma unroll
  for (int k = 0; k < 3; ++k) { int i = t * 3 + k; if (i < NBUCK) { boff[i] = pre; pre += v[k]; } }
  if (t == 1023) boff[NBUCK] = sd[1023];
}

__global__ __launch_bounds__(256) void k_bin2(EdgePtrs Eg, const int* bh, const int* boff, int* pairs) {
  __shared__ int cur[NBUCK];
  const int* mybh = bh + (size_t)blockIdx.x * NBUCK;
  for (int i = threadIdx.x; i < NBUCK; i += 256) cur[i] = boff[i] + mybh[i];
  __syncthreads();
  int lo = blockIdx.x * CHUNK;
  int hi = lo + CHUNK; if (hi > TOTEDGE) hi = TOTEDGE;
  for (int gid = lo + threadIdx.x; gid < hi; gid += 256) {
    int r = gid / NEDGE, e = gid - r * NEDGE;
    int d = Eg.d[r][e];
    int b = c_BOFF[r] + (d >> 8);
    int pos = atomicAdd(&cur[b], 1);            // LDS atomic: block-local only
    pairs[pos] = ((d & 255) << 24) | Eg.s[r][e];
  }
}

__global__ __launch_bounds__(256) void k_bsort(const int* pairs, const int* boff,
                                               int* rowptr, int* asx) {
  __shared__ int spl[8192];
  __shared__ int sout[8192];
  __shared__ int ssc[256];
  __shared__ int scur[256];
  int b = blockIdx.x, t = threadIdx.x;
  int r = 0;
#pragma unroll
  for (int q = 1; q < 9; ++q) r += (b >= c_BOFF[q]);
  int lo = boff[b], hi = boff[b + 1];
  int n = hi - lo; if (n > 8192) n = 8192;      // cannot trigger (max bucket ~4.2k)
  for (int i = t; i < n; i += 256) spl[i] = pairs[lo + i];
  ssc[t] = 0;
  __syncthreads();
  for (int i = t; i < n; i += 256) atomicAdd(&ssc[((unsigned)spl[i]) >> 24], 1);
  __syncthreads();
  int c = ssc[t];
  for (int o = 1; o < 256; o <<= 1) {           // inclusive scan
    int x = (t >= o) ? ssc[t - o] : 0; __syncthreads();
    ssc[t] += x; __syncthreads();
  }
  int excl = ssc[t] - c;
  scur[t] = excl;
  int nodeBase = (b - c_BOFF[r]) << 8;
  int segBase = c_ADOFF[r] + nodeBase;
  int nseg = c_NS[c_DST[r]] - nodeBase; if (nseg > 256) nseg = 256;
  if (t < nseg) rowptr[segBase + t] = lo + excl;
  if (b == 0 && t == 0) rowptr[TOTSEG] = TOTEDGE;
  __syncthreads();
  for (int i = t; i < n; i += 256) {
    int p = spl[i];
    int pos = atomicAdd(&scur[((unsigned)p) >> 24], 1);
    sout[pos] = p & 0xFFFFFF;
  }
  __syncthreads();
  for (int i = t; i < n; i += 256) asx[lo + i] = sout[i];
}

// ---------------- per-node attention logits, thread-per-node ----------------
struct AlphaP {
  const float* x0; const float* x1; const float* x2; const float* x3;
  float* als; float* ald;
  const float* wvs; const float* wvd;   // [9][64] each, this layer
  int act; int smask; int dmask;
};

__global__ __launch_bounds__(256) void k_alphas(AlphaP P) {
  __shared__ float sws[576];
  __shared__ float swd[576];
  for (int i = threadIdx.x; i < 576; i += 256) { sws[i] = P.wvs[i]; swd[i] = P.wvd[i]; }
  __syncthreads();
  int node = blockIdx.x * 256 + threadIdx.x;
  if (node >= TOTROWS) return;
  int t = (node >= c_XOFF[1]) + (node >= c_XOFF[2]) + (node >= c_XOFF[3]);
  int n = node - c_XOFF[t];
  const float* xt = t == 0 ? P.x0 : t == 1 ? P.x1 : t == 2 ? P.x2 : P.x3;
  const float4* rp = (const float4*)xt + (size_t)n * 16;
  float4 row[16];
#pragma unroll
  for (int k = 0; k < 16; ++k) row[k] = rp[k];
  if (P.act) {
#pragma unroll
    for (int k = 0; k < 16; ++k) {
      row[k].x = fmaxf(row[k].x, 0.f); row[k].y = fmaxf(row[k].y, 0.f);
      row[k].z = fmaxf(row[k].z, 0.f); row[k].w = fmaxf(row[k].w, 0.f);
    }
  }
#pragma unroll
  for (int r = 0; r < 9; ++r) {
    bool ns = ((P.smask >> r) & 1) && (c_SRC[r] == t);
    bool nd = ((P.dmask >> r) & 1) && (c_DST[r] == t);
    if (ns) {
      float s = 0.f;
#pragma unroll
      for (int k = 0; k < 16; ++k) {
        float4 w = *(const float4*)&sws[r * 64 + k * 4];
        s += row[k].x * w.x + row[k].y * w.y + row[k].z * w.z + row[k].w * w.w;
      }
      P.als[c_ASOFF[r] + n] = s;
    }
    if (nd) {
      float s = 0.f;
#pragma unroll
      for (int k = 0; k < 16; ++k) {
        float4 w = *(const float4*)&swd[r * 64 + k * 4];
        s += row[k].x * w.x + row[k].y * w.y + row[k].z * w.z + row[k].w * w.w;
      }
      P.ald[c_ADOFF[r] + n] = s;
    }
  }
}

// ---------------- per-edge alpha (fp16), two-pass via fp32 score scratch ----------------
struct SoftP {
  const float* als; const float* ald;
  const int* rowptr; const int* asx;
  float* sscr;                // fp32 score scratch (aliased in hs region; dead there)
  _Float16* esc;              // persistent per-edge alpha (fp16)
  int segLo; int segN;
};

__global__ void k_soft(SoftP S) {
  int gid = blockIdx.x * 256 + threadIdx.x;
  if (gid >= S.segN) return;
  int seg = S.segLo + gid;
  int r = (seg >= c_ADOFF[1]) + (seg >= c_ADOFF[2]) + (seg >= c_ADOFF[3]) +
          (seg >= c_ADOFF[4]) + (seg >= c_ADOFF[5]) + (seg >= c_ADOFF[6]) +
          (seg >= c_ADOFF[7]) + (seg >= c_ADOFF[8]);
  int asoff = c_ASOFF[r];
  int p0 = S.rowptr[seg], p1 = S.rowptr[seg + 1];
  if (p1 <= p0) return;
  float aldv = S.ald[seg];
  float m = -3.4e38f, z = 0.f;
  for (int i = p0; i < p1; ++i) {
    float s = S.als[asoff + S.asx[i]] + aldv;
    s = s >= 0.f ? s : 0.2f * s;
    S.sscr[i] = s;
    float mn = fmaxf(m, s);
    z = z * __expf(m - mn) + __expf(s - mn);
    m = mn;
  }
  float rz = 1.f / (z + 1e-16f);
  for (int i = p0; i < p1; ++i)
    S.esc[i] = (_Float16)(__expf(S.sscr[i] - m) * rz);
}

// ---------------- merged MFMA GEMM: all active relations of a layer in ONE launch ----------------
struct GemmAllP {
  const float* x0; const float* x1; const float* x2; const float* x3;
  const float* Wl;             // Wsrc + l*9*4096
  __hip_bfloat16* hs;          // concat base
  int act; int nrel;
  int tbase[10];               // tile offsets per active relation (+ total)
  int rel[9];                  // active relation ids
};

#define XSTR 72                // LDS row stride in shorts (144B = 16B-aligned, 2-way banks)

__global__ __launch_bounds__(256) void k_gemma(GemmAllP G) {
  __shared__ unsigned short sx[64 * XSTR];   // X tile, bf16
  __shared__ unsigned short sw[64 * XSTR];   // W^T, bf16  (sw[n][k])
  int bid = blockIdx.x;
  int k = 0;
#pragma unroll 8
  for (int q = 1; q < 9; ++q) if (q < G.nrel) k += (bid >= G.tbase[q]);
  int r = G.rel[k];
  int tile = bid - G.tbase[k];
  int st = c_SRC[r];
  int Ns = c_NS[st];
  const float* x = st == 0 ? G.x0 : st == 1 ? G.x1 : st == 2 ? G.x2 : G.x3;
  const float* W = G.Wl + r * 4096;
  __hip_bfloat16* hsb = G.hs + (size_t)c_ASOFF[r] * 64;
  int base = tile * 64;
  int tid = threadIdx.x;
  for (int kk = tid; kk < 1024; kk += 256) {
    int krow = kk >> 4;
    int c4 = (kk & 15) * 4;
    float4 v = ((const float4*)W)[kk];
    sw[(c4 + 0) * XSTR + krow] = f2bf(v.x);
    sw[(c4 + 1) * XSTR + krow] = f2bf(v.y);
    sw[(c4 + 2) * XSTR + krow] = f2bf(v.z);
    sw[(c4 + 3) * XSTR + krow] = f2bf(v.w);
  }
  for (int kk = tid; kk < 1024; kk += 256) {
    int row = kk >> 4;
    int c4 = (kk & 15) * 4;
    int gr = base + row;
    float4 v = make_float4(0.f, 0.f, 0.f, 0.f);
    if (gr < Ns) v = ((const float4*)x)[(size_t)gr * 16 + (kk & 15)];
    if (G.act) { v.x = fmaxf(v.x, 0.f); v.y = fmaxf(v.y, 0.f); v.z = fmaxf(v.z, 0.f); v.w = fmaxf(v.w, 0.f); }
    ushort4 u;
    u.x = f2bf(v.x); u.y = f2bf(v.y); u.z = f2bf(v.z); u.w = f2bf(v.w);
    *(ushort4*)&sx[row * XSTR + c4] = u;
  }
  __syncthreads();
  int w    = tid >> 6;
  int lane = tid & 63;
  int m    = lane & 15;
  int quad = lane >> 4;
  short8 a0 = *(const short8*)&sx[(w * 16 + m) * XSTR + quad * 8];
  short8 a1 = *(const short8*)&sx[(w * 16 + m) * XSTR + 32 + quad * 8];
  f32x4 acc[4];
#pragma unroll
  for (int cb = 0; cb < 4; ++cb) acc[cb] = (f32x4)(0.f);
#pragma unroll
  for (int cb = 0; cb < 4; ++cb) {
    short8 b0 = *(const short8*)&sw[(cb * 16 + m) * XSTR + quad * 8];
    short8 b1 = *(const short8*)&sw[(cb * 16 + m) * XSTR + 32 + quad * 8];
    acc[cb] = __builtin_amdgcn_mfma_f32_16x16x32_bf16(a0, b0, acc[cb], 0, 0, 0);
    acc[cb] = __builtin_amdgcn_mfma_f32_16x16x32_bf16(a1, b1, acc[cb], 0, 0, 0);
  }
#pragma unroll
  for (int reg = 0; reg < 4; ++reg) {
    int lr = base + w * 16 + quad * 4 + reg;
    if (lr < Ns) {
#pragma unroll
      for (int cb = 0; cb < 4; ++cb)
        hsb[(size_t)lr * 64 + cb * 16 + m] = __float2bfloat16(acc[cb][reg]);
    }
  }
}

// ---------------- fused gather: ALL relations of one dst type, precomputed alpha ----------------
struct GatherFP {
  const __hip_bfloat16* hs;    // full concat base (row = asoff + local src)
  const _Float16* esc;         // per-edge alpha, global edge position
  const int* rowptr; const int* asx;
  float* xout;                 // offset to dst type's base
  const float* bias;           // bsum slice (layer, dst type)
  int Nd; int nrel;
  int ad0, ad1, ad2;           // seg offsets per relation
  int as0, as1, as2;           // hs row offsets per relation
};

__global__ void k_gatherf(GatherFP A) {
  int gwid = (blockIdx.x * blockDim.x + threadIdx.x) >> 6;
  int lane = threadIdx.x & 63;
  int half = lane >> 5;
  int sl   = lane & 31;
  int node = gwid * 2 + half;
  if (node >= A.Nd) return;
  float2 acc = ((const float2*)A.bias)[sl];
#pragma unroll 3
  for (int k = 0; k < 3; ++k) {
    if (k >= A.nrel) break;
    int ad = k == 0 ? A.ad0 : (k == 1 ? A.ad1 : A.ad2);
    int as = k == 0 ? A.as0 : (k == 1 ? A.as1 : A.as2);
    int seg = ad + node;
    int p0 = A.rowptr[seg], p1 = A.rowptr[seg + 1];
    if (p1 <= p0) continue;
    const __hip_bfloat16* hsb = A.hs + (size_t)as * 64;
    int j = p0;
    for (; j + 4 <= p1; j += 4) {   // 4 independent row loads in flight
      int ls0 = A.asx[j], ls1 = A.asx[j + 1], ls2 = A.asx[j + 2], ls3 = A.asx[j + 3];
      float a0 = (float)A.esc[j],     a1 = (float)A.esc[j + 1];
      float a2 = (float)A.esc[j + 2], a3 = (float)A.esc[j + 3];
      unsigned h0 = *(const unsigned*)&hsb[(size_t)ls0 * 64 + sl * 2];
      unsigned h1 = *(const unsigned*)&hsb[(size_t)ls1 * 64 + sl * 2];
      unsigned h2 = *(const unsigned*)&hsb[(size_t)ls2 * 64 + sl * 2];
      unsigned h3 = *(const unsigned*)&hsb[(size_t)ls3 * 64 + sl * 2];
      acc.x = fmaf(a0, __uint_as_float(h0 << 16), acc.x);
      acc.y = fmaf(a0, __uint_as_float(h0 & 0xffff0000u), acc.y);
      acc.x = fmaf(a1, __uint_as_float(h1 << 16), acc.x);
      acc.y = fmaf(a1, __uint_as_float(h1 & 0xffff0000u), acc.y);
      acc.x = fmaf(a2, __uint_as_float(h2 << 16), acc.x);
      acc.y = fmaf(a2, __uint_as_float(h2 & 0xffff0000u), acc.y);
      acc.x = fmaf(a3, __uint_as_float(h3 << 16), acc.x);
      acc.y = fmaf(a3, __uint_as_float(h3 & 0xffff0000u), acc.y);
    }
    for (; j < p1; ++j) {
      int ls = A.asx[j];
      float aj = (float)A.esc[j];
      unsigned hv = *(const unsigned*)&hsb[(size_t)ls * 64 + sl * 2];
      acc.x = fmaf(aj, __uint_as_float(hv << 16), acc.x);
      acc.y = fmaf(aj, __uint_as_float(hv & 0xffff0000u), acc.y);
    }
  }
  *(float2*)&A.xout[(size_t)node * 64 + sl * 2] = acc;
}

// ---------------- pooling: ATOMIC-FREE segmented reduction over sorted batch ----------------
__global__ void k_gbound(const int* bvar, const int* bcon, int* gs0, int* gs3) {
  int gid = blockIdx.x * 256 + threadIdx.x;
  const int N0 = 100000, N3 = 80000;
  if (gid < N0) {
    int i = gid;
    int b = bvar[i];
    int bp = i ? bvar[i - 1] : -1;
    for (int g = bp + 1; g <= b; ++g) gs0[g] = i;
    if (i == N0 - 1) for (int g = b + 1; g <= 64; ++g) gs0[g] = N0;
  } else if (gid < N0 + N3) {
    int i = gid - N0;
    int b = bcon[i];
    int bp = i ? bcon[i - 1] : -1;
    for (int g = bp + 1; g <= b; ++g) gs3[g] = i;
    if (i == N3 - 1) for (int g = b + 1; g <= 64; ++g) gs3[g] = N3;
  }
}

__global__ __launch_bounds__(256) void k_pool2(const float* xfin, const int* gs0, const int* gs3,
                                               float* partial) {
  __shared__ float4 sdv[256];
  int b = blockIdx.x;
  int sp = b >> 7;
  int rem = b & 127;
  int g = rem >> 1;
  int t = rem & 1;                    // 0 -> type0, 1 -> type3
  const int* gs = t ? gs3 : gs0;
  int xbase = t ? 170000 : 0;
  int lo = gs[g], hi = gs[g + 1];
  int len = hi - lo;
  int r0 = lo + (len * sp) / 8;
  int r1 = lo + (len * (sp + 1)) / 8;
  int tid = threadIdx.x;
  int rp = tid >> 4;                  // 16 rows in flight
  int cq = tid & 15;                  // column quad
  float4 acc = make_float4(0.f, 0.f, 0.f, 0.f);
  for (int row = r0 + rp; row < r1; row += 16) {
    float4 v = ((const float4*)xfin)[(size_t)(xbase + row) * 16 + cq];
    acc.x += fmaxf(v.x, 0.f); acc.y += fmaxf(v.y, 0.f);
    acc.z += fmaxf(v.z, 0.f); acc.w += fmaxf(v.w, 0.f);
  }
  sdv[tid] = acc;
  __syncthreads();
  for (int o = 128; o >= 16; o >>= 1) {
    if (tid < o) {
      float4 a = sdv[tid], c = sdv[tid + o];
      a.x += c.x; a.y += c.y; a.z += c.z; a.w += c.w;
      sdv[tid] = a;
    }
    __syncthreads();
  }
  if (tid < 16) ((float4*)&partial[(size_t)b * 64])[tid] = sdv[tid];
}

__global__ void k_poolred2(const float* partial, float* pool) {
  int g = blockIdx.x >> 1;
  int t = blockIdx.x & 1;
  int col = threadIdx.x;
  float s = 0.f;
#pragma unroll
  for (int sp = 0; sp < 8; ++sp)
    s += partial[(size_t)(((sp << 7) | (g << 1) | t)) * 64 + col];
  pool[(t ? 4096 : 0) + g * 64 + col] = s;
}

__global__ void k_final(const float* pool, const int* gs0, const int* gs3,
                        const float* lin_w, const float* lin_b, float* out) {
  int k = threadIdx.x;          // 128 = 64 graphs x 2 outputs
  int g = k >> 1, o = k & 1;
  float c0 = fmaxf((float)(gs0[g + 1] - gs0[g]), 1.f);
  float c3 = fmaxf((float)(gs3[g + 1] - gs3[g]), 1.f);
  float acc = lin_b[o];
  for (int i = 0; i < 64; ++i) {
    acc += (pool[g * 64 + i] / c0) * lin_w[o * 128 + i];
    acc += (pool[4096 + g * 64 + i] / c3) * lin_w[o * 128 + 64 + i];
  }
  out[g * 2 + o] = acc;
}

__global__ void k_bail(float* out) {
  if (threadIdx.x < 128) out[threadIdx.x] = 0.f;
}

// ---------------- host launch ----------------
extern "C" void kernel_launch(void* const* d_in, const int* in_sizes, int n_in,
                              void* d_out, int out_size, void* d_ws, size_t ws_size,
                              hipStream_t stream) {
  (void)in_sizes; (void)n_in; (void)out_size;
  // ---- workspace layout (float units) ----
  const size_t O_XA   = 0;            // 16,000,000 (layer-1 out; layer-2 writes types 0/3 in place)
  const size_t O_HS   = 16000000;     // 21,120,000 (bf16 hs: 660k rows x 64 x 2B)
                                      //   aliases (each dead before hs is written that layer):
                                      //   CSR arrays (l1 pre-gemm); sscr fp32[2.7M] during k_soft
  const size_t O_ALS  = 37120000;     //    660,000
  const size_t O_ALD  = 37780000;     //    660,000
  const size_t O_ESC  = 38440000;     //  1,350,000 (fp16[2.7M] per-edge alpha)
  const size_t O_WV   = 39790000;     //      2,304
  const size_t O_BS   = 39792304;     //        512
  const size_t O_RP   = 39792816;     //    660,016 (int; 660,001 used)
  const size_t O_ASX  = 40452832;     //  2,700,000 (int)
  const size_t O_GS   = 43152832;     //        256 (int; gs0[65]+gs3[65])
  const size_t O_PART = 43153088;     //     65,536 (1024 blocks x 64)
  const size_t O_POOL = 43218624;     //      8,192
  const size_t NEED   = 43226816;     // floats (~172.9 MB; 177.6 MB proven available)

  if (ws_size < NEED * 4) {           // graceful, deterministic bail (diagnostic)
    k_bail<<<1, 128, 0, stream>>>((float*)d_out);
    return;
  }

  const float* x0 = (const float*)d_in[0];
  const float* x1 = (const float*)d_in[1];
  const float* x2 = (const float*)d_in[2];
  const float* x3 = (const float*)d_in[3];
  const float* Wsrc = (const float*)d_in[4];
  const float* Wdst = (const float*)d_in[5];
  const float* asrc = (const float*)d_in[6];
  const float* adst = (const float*)d_in[7];
  const float* bias = (const float*)d_in[8];
  const float* lin_w = (const float*)d_in[9];
  const float* lin_b = (const float*)d_in[10];
  EdgePtrs Eg;
  for (int r = 0; r < 9; ++r) {
    Eg.s[r] = (const int*)d_in[11 + 2 * r];
    Eg.d[r] = (const int*)d_in[12 + 2 * r];
  }
  const int* bvar = (const int*)d_in[29];
  const int* bcon = (const int*)d_in[30];

  float* ws = (float*)d_ws;
  float* xA   = ws + O_XA;
  __hip_bfloat16* hs = (__hip_bfloat16*)(ws + O_HS);
  int* bh     = (int*)(ws + O_HS);                 // alias, dead before gemms
  int* pairs  = bh + 1704780;                      // alias
  int* gbh    = pairs + 2700000;                   // alias
  int* boff   = gbh + 2584;                        // alias
  int* csum   = boff + 2592;                       // alias (KCH*NBUCK = 51,660)
  float* sscr = ws + O_HS;                         // alias: score scratch during k_soft
  float* als  = ws + O_ALS;
  float* ald  = ws + O_ALD;
  _Float16* esc = (_Float16*)(ws + O_ESC);
  float* wv   = ws + O_WV;
  float* bsum = ws + O_BS;
  int* rowptr = (int*)(ws + O_RP);
  int* asx    = (int*)(ws + O_ASX);
  int* gs0    = (int*)(ws + O_GS);
  int* gs3    = gs0 + 65;
  float* partial = ws + O_PART;
  float* pool = ws + O_POOL;

  const int h_NS[4]   = {100000, 20000, 50000, 80000};
  const int h_SRC[9]  = {0,0,0,2,3,1,2,3,3};
  const int h_XOFF[4] = {0,100000,120000,170000};

  // fused-gather tables: per dst type, its relations (seg offset, hs row offset)
  const int g_nrel[4]     = {3, 1, 2, 3};
  const int g_ad[4][3]    = {{310000,410000,510000},{0,0,0},{20000,610000,0},{70000,150000,230000}};
  const int g_as[4][3]    = {{430000,450000,500000},{0,0,0},{100000,580000,0},{200000,300000,350000}};

  k_setup<<<37, 64, 0, stream>>>(Wsrc, Wdst, asrc, adst, bias, wv, bsum);

  // CSR build: deterministic block-private bucket sort, zero global atomics
  k_bhist2<<<NBLK, 256, 0, stream>>>(Eg, bh);
  k_cs1<<<KCH * 11, 256, 0, stream>>>(bh, csum);
  k_cs2<<<11, 256, 0, stream>>>(csum, gbh);
  k_cs3<<<KCH * 11, 256, 0, stream>>>(bh, csum);
  k_bscan<<<1, 1024, 0, stream>>>(gbh, boff);
  k_bin2<<<NBLK, 256, 0, stream>>>(Eg, bh, boff, pairs);
  k_bsort<<<NBUCK, 256, 0, stream>>>(pairs, boff, rowptr, asx);
  k_gbound<<<(180000 + 255) / 256, 256, 0, stream>>>(bvar, bcon, gs0, gs3);

  for (int l = 0; l < 2; ++l) {
    const float* xin[4];
    if (l == 0) { xin[0] = x0; xin[1] = x1; xin[2] = x2; xin[3] = x3; }
    else {
      for (int t = 0; t < 4; ++t) xin[t] = xA + (size_t)h_XOFF[t] * 64;
    }
    int act = (l > 0);
    int relmask = l ? 0x0FC : 0x1FF;   // layer 2: dst types 1,2 unused -> skip r0,r1,r8

    AlphaP AP;
    AP.x0 = xin[0]; AP.x1 = xin[1]; AP.x2 = xin[2]; AP.x3 = xin[3];
    AP.als = als; AP.ald = ald;
    AP.wvs = wv + l * 576; AP.wvd = wv + 1152 + l * 576;
    AP.act = act; AP.smask = relmask; AP.dmask = relmask;
    k_alphas<<<(TOTROWS + 255) / 256, 256, 0, stream>>>(AP);

    SoftP SP;
    SP.als = als; SP.ald = ald; SP.rowptr = rowptr; SP.asx = asx;
    SP.sscr = sscr; SP.esc = esc;
    SP.segLo = l ? 70000 : 0;                 // layer 2: segs of r2..r7 are contiguous
    SP.segN  = l ? 540000 : TOTSEG;
    k_soft<<<(SP.segN + 255) / 256, 256, 0, stream>>>(SP);

    // ONE merged MFMA-GEMM launch for all active relations of this layer
    GemmAllP G;
    G.x0 = xin[0]; G.x1 = xin[1]; G.x2 = xin[2]; G.x3 = xin[3];
    G.Wl = Wsrc + (size_t)l * 9 * 4096;
    G.hs = hs; G.act = act;
    int nrel = 0, cum = 0;
    for (int r = 0; r < 9; ++r) {
      if (!((relmask >> r) & 1)) continue;
      G.rel[nrel] = r;
      G.tbase[nrel] = cum;
      cum += (h_NS[h_SRC[r]] + 63) / 64;
      ++nrel;
    }
    G.nrel = nrel; G.tbase[nrel] = cum;
    k_gemma<<<cum, 256, 0, stream>>>(G);

    for (int t = 0; t < 4; ++t) {
      if (l == 1 && (t == 1 || t == 2)) continue;   // dead outputs in layer 2
      GatherFP A;
      A.hs = hs; A.esc = esc;
      A.rowptr = rowptr; A.asx = asx;
      A.xout = xA + (size_t)h_XOFF[t] * 64;         // layer 2 writes xA in place (xA dead post-gemm)
      A.bias = bsum + (l * 4 + t) * 64;
      A.Nd = h_NS[t]; A.nrel = g_nrel[t];
      A.ad0 = g_ad[t][0]; A.ad1 = g_ad[t][1]; A.ad2 = g_ad[t][2];
      A.as0 = g_as[t][0]; A.as1 = g_as[t][1]; A.as2 = g_as[t][2];
      k_gatherf<<<(A.Nd + 7) / 8, 256, 0, stream>>>(A);
    }
  }

  k_pool2<<<1024, 256, 0, stream>>>(xA, gs0, gs3, partial);
  k_poolred2<<<128, 64, 0, stream>>>(partial, pool);
  k_final<<<1, 128, 0, stream>>>(pool, gs0, gs3, lin_w, lin_b, (float*)d_out);
}

// Round 14
// 664.086 us; speedup vs baseline: 1.0203x; 1.0203x over previous
//
#include <hip/hip_runtime.h>
#include <hip/hip_bf16.h>

#define NH 64
#define NRELS 9
#define NEDGE 300000
#define NGRAPH 64
#define TOTROWS 250000
#define TOTSEG 660000
#define TOTEDGE (NRELS * NEDGE)
#define NBUCK 2583           // sum over r of ceil(Nd_r/256)
#define CHUNK 2048           // edges per block in binning passes (grid 1319 blocks)
#define NBLK ((TOTEDGE + CHUNK - 1) / CHUNK)   // 1319
#define KCH 20               // scan chunks over NBLK
#define KSP 66               // NBLK rows per scan chunk (20*66 >= 1319)

typedef __attribute__((ext_vector_type(8))) short short8;
typedef __attribute__((ext_vector_type(4))) float f32x4;

__constant__ int c_NS[4]     = {100000, 20000, 50000, 80000};
__constant__ int c_SRC[9]    = {0,0,0,2,3,1,2,3,3};
__constant__ int c_DST[9]    = {1,2,3,3,3,0,0,0,2};
__constant__ int c_XOFF[5]   = {0,100000,120000,170000,250000};
__constant__ int c_ASOFF[10] = {0,100000,200000,300000,350000,430000,450000,500000,580000,660000};
__constant__ int c_ADOFF[10] = {0,20000,70000,150000,230000,310000,410000,510000,610000,660000};
__constant__ int c_BOFF[9]   = {0,79,275,588,901,1214,1605,1996,2387};  // bucket base per relation
// fused-gather tables: per dst type, its relations (seg offset, hs row offset)
__constant__ int c_GNREL[4]  = {3, 1, 2, 3};
__constant__ int c_GAD[4][3] = {{310000,410000,510000},{0,0,0},{20000,610000,0},{70000,150000,230000}};
__constant__ int c_GAS[4][3] = {{430000,450000,500000},{0,0,0},{100000,580000,0},{200000,300000,350000}};

struct EdgePtrs { const int* s[9]; const int* d[9]; };

__device__ __forceinline__ unsigned short f2bf(float f) {
  union { __hip_bfloat16 h; unsigned short u; } c;
  c.h = __float2bfloat16(f);
  return c.u;
}

// ---------------- setup: wv_s/wv_d = W @ a  (per l,r,side), bias presums ----------------
__global__ void k_setup(const float* Wsrc, const float* Wdst, const float* asrc,
                        const float* adst, const float* bias, float* wv, float* bsum) {
  int b = blockIdx.x, j = threadIdx.x;
  if (b < 36) {
    int r = b % 9, q = b / 9;
    int l = q >> 1, side = q & 1;
    const float* W = (side ? Wdst : Wsrc) + (l * 9 + r) * 64 * 64;
    const float* a = (side ? adst : asrc) + (l * 9 + r) * 64;
    float s = 0.f;
    for (int i = 0; i < 64; ++i) s += W[j * 64 + i] * a[i];
    wv[(side ? 1152 : 0) + (l * 9 + r) * 64 + j] = s;
  } else {
    for (int l = 0; l < 2; ++l)
      for (int t = 0; t < 4; ++t) {
        float s = 0.f;
        for (int r = 0; r < 9; ++r)
          if (c_DST[r] == t) s += bias[(l * 9 + r) * 64 + j];
        bsum[(l * 4 + t) * 64 + j] = s;
      }
  }
}

// ---------------- CSR build: deterministic block-private bucket sort (no global atomics) ----
__global__ __launch_bounds__(256) void k_bhist2(EdgePtrs Eg, int* bh) {
  __shared__ int sh[NBUCK];
  for (int i = threadIdx.x; i < NBUCK; i += 256) sh[i] = 0;
  __syncthreads();
  int lo = blockIdx.x * CHUNK;
  int hi = lo + CHUNK; if (hi > TOTEDGE) hi = TOTEDGE;
  for (int gid = lo + threadIdx.x; gid < hi; gid += 256) {
    int r = gid / NEDGE, e = gid - r * NEDGE;
    int d = Eg.d[r][e];
    atomicAdd(&sh[c_BOFF[r] + (d >> 8)], 1);
  }
  __syncthreads();
  int* dst = bh + (size_t)blockIdx.x * NBUCK;
  for (int i = threadIdx.x; i < NBUCK; i += 256) dst[i] = sh[i];
}

// 3-phase column scan
__global__ void k_cs1(const int* bh, int* csum) {
  int blk = blockIdx.x;               // 0..KCH*11-1
  int c = blk / 11;
  int b = (blk % 11) * 256 + threadIdx.x;
  if (b >= NBUCK) return;
  int k0 = c * KSP;
  int k1 = k0 + KSP; if (k1 > NBLK) k1 = NBLK;
  int s = 0;
  for (int k = k0; k < k1; ++k) s += bh[(size_t)k * NBUCK + b];
  csum[(size_t)c * NBUCK + b] = s;
}

__global__ void k_cs2(int* csum, int* gbh) {
  int b = blockIdx.x * 256 + threadIdx.x;
  if (b >= NBUCK) return;
  int run = 0;
#pragma unroll
  for (int c = 0; c < KCH; ++c) {
    size_t idx = (size_t)c * NBUCK + b;
    int t = csum[idx];
    csum[idx] = run;
    run += t;
  }
  gbh[b] = run;
}

__global__ void k_cs3(int* bh, const int* csum) {
  int blk = blockIdx.x;
  int c = blk / 11;
  int b = (blk % 11) * 256 + threadIdx.x;
  if (b >= NBUCK) return;
  int k0 = c * KSP;
  int k1 = k0 + KSP; if (k1 > NBLK) k1 = NBLK;
  int run = csum[(size_t)c * NBUCK + b];
  for (int k = k0; k < k1; ++k) {
    size_t idx = (size_t)k * NBUCK + b;
    int t = bh[idx];
    bh[idx] = run;
    run += t;
  }
}

__global__ void k_bscan(const int* gbh, int* boff) {
  __shared__ int sd[1024];
  int t = threadIdx.x;
  int v[3]; int s = 0;
#pragma unroll
  for (int k = 0; k < 3; ++k) { int i = t * 3 + k; v[k] = (i < NBUCK) ? gbh[i] : 0; s += v[k]; }
  sd[t] = s; __syncthreads();
  for (int o = 1; o < 1024; o <<= 1) {
    int x = (t >= o) ? sd[t - o] : 0; __syncthreads();
    sd[t] += x; __syncthreads();
  }
  int pre = sd[t] - s;
#pragma unroll
  for (int k = 0; k < 3; ++k) { int i = t * 3 + k; if (i < NBUCK) { boff[i] = pre; pre += v[k]; } }
  if (t == 1023) boff[NBUCK] = sd[1023];
}

__global__ __launch_bounds__(256) void k_bin2(EdgePtrs Eg, const int* bh, const int* boff, int* pairs) {
  __shared__ int cur[NBUCK];
  const int* mybh = bh + (size_t)blockIdx.x * NBUCK;
  for (int i = threadIdx.x; i < NBUCK; i += 256) cur[i] = boff[i] + mybh[i];
  __syncthreads();
  int lo = blockIdx.x * CHUNK;
  int hi = lo + CHUNK; if (hi > TOTEDGE) hi = TOTEDGE;
  for (int gid = lo + threadIdx.x; gid < hi; gid += 256) {
    int r = gid / NEDGE, e = gid - r * NEDGE;
    int d = Eg.d[r][e];
    int b = c_BOFF[r] + (d >> 8);
    int pos = atomicAdd(&cur[b], 1);            // LDS atomic: block-local only
    pairs[pos] = ((d & 255) << 24) | Eg.s[r][e];
  }
}

__global__ __launch_bounds__(256) void k_bsort(const int* pairs, const int* boff,
                                               int* rowptr, int* asx) {
  __shared__ int spl[8192];
  __shared__ int sout[8192];
  __shared__ int ssc[256];
  __shared__ int scur[256];
  int b = blockIdx.x, t = threadIdx.x;
  int r = 0;
#pragma unroll
  for (int q = 1; q < 9; ++q) r += (b >= c_BOFF[q]);
  int lo = boff[b], hi = boff[b + 1];
  int n = hi - lo; if (n > 8192) n = 8192;      // cannot trigger (max bucket ~4.2k)
  for (int i = t; i < n; i += 256) spl[i] = pairs[lo + i];
  ssc[t] = 0;
  __syncthreads();
  for (int i = t; i < n; i += 256) atomicAdd(&ssc[((unsigned)spl[i]) >> 24], 1);
  __syncthreads();
  int c = ssc[t];
  for (int o = 1; o < 256; o <<= 1) {           // inclusive scan
    int x = (t >= o) ? ssc[t - o] : 0; __syncthreads();
    ssc[t] += x; __syncthreads();
  }
  int excl = ssc[t] - c;
  scur[t] = excl;
  int nodeBase = (b - c_BOFF[r]) << 8;
  int segBase = c_ADOFF[r] + nodeBase;
  int nseg = c_NS[c_DST[r]] - nodeBase; if (nseg > 256) nseg = 256;
  if (t < nseg) rowptr[segBase + t] = lo + excl;
  if (b == 0 && t == 0) rowptr[TOTSEG] = TOTEDGE;
  __syncthreads();
  for (int i = t; i < n; i += 256) {
    int p = spl[i];
    int pos = atomicAdd(&scur[((unsigned)p) >> 24], 1);
    sout[pos] = p & 0xFFFFFF;
  }
  __syncthreads();
  for (int i = t; i < n; i += 256) asx[lo + i] = sout[i];
}

// ---------------- per-node attention logits, thread-per-node ----------------
struct AlphaP {
  const float* x0; const float* x1; const float* x2; const float* x3;
  float* als; float* ald;
  const float* wvs; const float* wvd;   // [9][64] each, this layer
  int act; int smask; int dmask;
};

__global__ __launch_bounds__(256) void k_alphas(AlphaP P) {
  __shared__ float sws[576];
  __shared__ float swd[576];
  for (int i = threadIdx.x; i < 576; i += 256) { sws[i] = P.wvs[i]; swd[i] = P.wvd[i]; }
  __syncthreads();
  int node = blockIdx.x * 256 + threadIdx.x;
  if (node >= TOTROWS) return;
  int t = (node >= c_XOFF[1]) + (node >= c_XOFF[2]) + (node >= c_XOFF[3]);
  int n = node - c_XOFF[t];
  const float* xt = t == 0 ? P.x0 : t == 1 ? P.x1 : t == 2 ? P.x2 : P.x3;
  const float4* rp = (const float4*)xt + (size_t)n * 16;
  float4 row[16];
#pragma unroll
  for (int k = 0; k < 16; ++k) row[k] = rp[k];
  if (P.act) {
#pragma unroll
    for (int k = 0; k < 16; ++k) {
      row[k].x = fmaxf(row[k].x, 0.f); row[k].y = fmaxf(row[k].y, 0.f);
      row[k].z = fmaxf(row[k].z, 0.f); row[k].w = fmaxf(row[k].w, 0.f);
    }
  }
#pragma unroll
  for (int r = 0; r < 9; ++r) {
    bool ns = ((P.smask >> r) & 1) && (c_SRC[r] == t);
    bool nd = ((P.dmask >> r) & 1) && (c_DST[r] == t);
    if (ns) {
      float s = 0.f;
#pragma unroll
      for (int k = 0; k < 16; ++k) {
        float4 w = *(const float4*)&sws[r * 64 + k * 4];
        s += row[k].x * w.x + row[k].y * w.y + row[k].z * w.z + row[k].w * w.w;
      }
      P.als[c_ASOFF[r] + n] = s;
    }
    if (nd) {
      float s = 0.f;
#pragma unroll
      for (int k = 0; k < 16; ++k) {
        float4 w = *(const float4*)&swd[r * 64 + k * 4];
        s += row[k].x * w.x + row[k].y * w.y + row[k].z * w.z + row[k].w * w.w;
      }
      P.ald[c_ADOFF[r] + n] = s;
    }
  }
}

// ---------------- per-edge alpha (fp16), two-pass via fp32 score scratch ----------------
struct SoftP {
  const float* als; const float* ald;
  const int* rowptr; const int* asx;
  float* sscr;                // fp32 score scratch (aliased in hs region; dead there)
  _Float16* esc;              // persistent per-edge alpha (fp16)
  int segLo; int segN;
};

__global__ void k_soft(SoftP S) {
  int gid = blockIdx.x * 256 + threadIdx.x;
  if (gid >= S.segN) return;
  int seg = S.segLo + gid;
  int r = (seg >= c_ADOFF[1]) + (seg >= c_ADOFF[2]) + (seg >= c_ADOFF[3]) +
          (seg >= c_ADOFF[4]) + (seg >= c_ADOFF[5]) + (seg >= c_ADOFF[6]) +
          (seg >= c_ADOFF[7]) + (seg >= c_ADOFF[8]);
  int asoff = c_ASOFF[r];
  int p0 = S.rowptr[seg], p1 = S.rowptr[seg + 1];
  if (p1 <= p0) return;
  float aldv = S.ald[seg];
  float m = -3.4e38f, z = 0.f;
  for (int i = p0; i < p1; ++i) {
    float s = S.als[asoff + S.asx[i]] + aldv;
    s = s >= 0.f ? s : 0.2f * s;
    S.sscr[i] = s;
    float mn = fmaxf(m, s);
    z = z * __expf(m - mn) + __expf(s - mn);
    m = mn;
  }
  float rz = 1.f / (z + 1e-16f);
  for (int i = p0; i < p1; ++i)
    S.esc[i] = (_Float16)(__expf(S.sscr[i] - m) * rz);
}

// ---------------- merged MFMA GEMM: all active relations of a layer in ONE launch ----------------
struct GemmAllP {
  const float* x0; const float* x1; const float* x2; const float* x3;
  const float* Wl;             // Wsrc + l*9*4096
  __hip_bfloat16* hs;          // concat base
  int act; int nrel;
  int tbase[10];               // tile offsets per active relation (+ total)
  int rel[9];                  // active relation ids
};

#define XSTR 72                // LDS row stride in shorts (144B = 16B-aligned, 2-way banks)

__global__ __launch_bounds__(256) void k_gemma(GemmAllP G) {
  __shared__ unsigned short sx[64 * XSTR];   // X tile, bf16
  __shared__ unsigned short sw[64 * XSTR];   // W^T, bf16  (sw[n][k])
  int bid = blockIdx.x;
  int k = 0;
#pragma unroll 8
  for (int q = 1; q < 9; ++q) if (q < G.nrel) k += (bid >= G.tbase[q]);
  int r = G.rel[k];
  int tile = bid - G.tbase[k];
  int st = c_SRC[r];
  int Ns = c_NS[st];
  const float* x = st == 0 ? G.x0 : st == 1 ? G.x1 : st == 2 ? G.x2 : G.x3;
  const float* W = G.Wl + r * 4096;
  __hip_bfloat16* hsb = G.hs + (size_t)c_ASOFF[r] * 64;
  int base = tile * 64;
  int tid = threadIdx.x;
  for (int kk = tid; kk < 1024; kk += 256) {
    int krow = kk >> 4;
    int c4 = (kk & 15) * 4;
    float4 v = ((const float4*)W)[kk];
    sw[(c4 + 0) * XSTR + krow] = f2bf(v.x);
    sw[(c4 + 1) * XSTR + krow] = f2bf(v.y);
    sw[(c4 + 2) * XSTR + krow] = f2bf(v.z);
    sw[(c4 + 3) * XSTR + krow] = f2bf(v.w);
  }
  for (int kk = tid; kk < 1024; kk += 256) {
    int row = kk >> 4;
    int c4 = (kk & 15) * 4;
    int gr = base + row;
    float4 v = make_float4(0.f, 0.f, 0.f, 0.f);
    if (gr < Ns) v = ((const float4*)x)[(size_t)gr * 16 + (kk & 15)];
    if (G.act) { v.x = fmaxf(v.x, 0.f); v.y = fmaxf(v.y, 0.f); v.z = fmaxf(v.z, 0.f); v.w = fmaxf(v.w, 0.f); }
    ushort4 u;
    u.x = f2bf(v.x); u.y = f2bf(v.y); u.z = f2bf(v.z); u.w = f2bf(v.w);
    *(ushort4*)&sx[row * XSTR + c4] = u;
  }
  __syncthreads();
  int w    = tid >> 6;
  int lane = tid & 63;
  int m    = lane & 15;
  int quad = lane >> 4;
  short8 a0 = *(const short8*)&sx[(w * 16 + m) * XSTR + quad * 8];
  short8 a1 = *(const short8*)&sx[(w * 16 + m) * XSTR + 32 + quad * 8];
  f32x4 acc[4];
#pragma unroll
  for (int cb = 0; cb < 4; ++cb) acc[cb] = (f32x4)(0.f);
#pragma unroll
  for (int cb = 0; cb < 4; ++cb) {
    short8 b0 = *(const short8*)&sw[(cb * 16 + m) * XSTR + quad * 8];
    short8 b1 = *(const short8*)&sw[(cb * 16 + m) * XSTR + 32 + quad * 8];
    acc[cb] = __builtin_amdgcn_mfma_f32_16x16x32_bf16(a0, b0, acc[cb], 0, 0, 0);
    acc[cb] = __builtin_amdgcn_mfma_f32_16x16x32_bf16(a1, b1, acc[cb], 0, 0, 0);
  }
#pragma unroll
  for (int reg = 0; reg < 4; ++reg) {
    int lr = base + w * 16 + quad * 4 + reg;
    if (lr < Ns) {
#pragma unroll
      for (int cb = 0; cb < 4; ++cb)
        hsb[(size_t)lr * 64 + cb * 16 + m] = __float2bfloat16(acc[cb][reg]);
    }
  }
}

// ---------------- merged gather: ALL active dst types of a layer in ONE launch ----------------
struct GatherAllP {
  const __hip_bfloat16* hs;    // full concat base
  const _Float16* esc;         // per-edge alpha, global edge position
  const int* rowptr; const int* asx;
  float* xA;                   // x buffer base
  const float* bsum;           // bsum + l*256
  int ntypes;
  int tbase[5];                // block offsets per active type (+ total)
  int typ[4];                  // dst type per slot
};

__global__ void k_gatherall(GatherAllP A) {
  int bid = blockIdx.x;
  int k = 0;
#pragma unroll 3
  for (int q = 1; q < 4; ++q) if (q < A.ntypes) k += (bid >= A.tbase[q]);
  int t = A.typ[k];
  int Nd = c_NS[t];
  int lane = threadIdx.x & 63;
  int half = lane >> 5;
  int sl   = lane & 31;
  int node = (bid - A.tbase[k]) * 8 + (threadIdx.x >> 6) * 2 + half;
  if (node >= Nd) return;
  float* xout = A.xA + (size_t)c_XOFF[t] * 64;
  float2 acc = ((const float2*)(A.bsum + t * 64))[sl];
  int nrel = c_GNREL[t];
#pragma unroll 3
  for (int kk = 0; kk < 3; ++kk) {
    if (kk >= nrel) break;
    int ad = c_GAD[t][kk];
    int as = c_GAS[t][kk];
    int seg = ad + node;
    int p0 = A.rowptr[seg], p1 = A.rowptr[seg + 1];
    if (p1 <= p0) continue;
    const __hip_bfloat16* hsb = A.hs + (size_t)as * 64;
    int j = p0;
    for (; j + 4 <= p1; j += 4) {   // 4 independent row loads in flight
      int ls0 = A.asx[j], ls1 = A.asx[j + 1], ls2 = A.asx[j + 2], ls3 = A.asx[j + 3];
      float a0 = (float)A.esc[j],     a1 = (float)A.esc[j + 1];
      float a2 = (float)A.esc[j + 2], a3 = (float)A.esc[j + 3];
      unsigned h0 = *(const unsigned*)&hsb[(size_t)ls0 * 64 + sl * 2];
      unsigned h1 = *(const unsigned*)&hsb[(size_t)ls1 * 64 + sl * 2];
      unsigned h2 = *(const unsigned*)&hsb[(size_t)ls2 * 64 + sl * 2];
      unsigned h3 = *(const unsigned*)&hsb[(size_t)ls3 * 64 + sl * 2];
      acc.x = fmaf(a0, __uint_as_float(h0 << 16), acc.x);
      acc.y = fmaf(a0, __uint_as_float(h0 & 0xffff0000u), acc.y);
      acc.x = fmaf(a1, __uint_as_float(h1 << 16), acc.x);
      acc.y = fmaf(a1, __uint_as_float(h1 & 0xffff0000u), acc.y);
      acc.x = fmaf(a2, __uint_as_float(h2 << 16), acc.x);
      acc.y = fmaf(a2, __uint_as_float(h2 & 0xffff0000u), acc.y);
      acc.x = fmaf(a3, __uint_as_float(h3 << 16), acc.x);
      acc.y = fmaf(a3, __uint_as_float(h3 & 0xffff0000u), acc.y);
    }
    for (; j < p1; ++j) {
      int ls = A.asx[j];
      float aj = (float)A.esc[j];
      unsigned hv = *(const unsigned*)&hsb[(size_t)ls * 64 + sl * 2];
      acc.x = fmaf(aj, __uint_as_float(hv << 16), acc.x);
      acc.y = fmaf(aj, __uint_as_float(hv & 0xffff0000u), acc.y);
    }
  }
  *(float2*)&xout[(size_t)node * 64 + sl * 2] = acc;
}

// ---------------- pooling: ATOMIC-FREE segmented reduction over sorted batch ----------------
__global__ void k_gbound(const int* bvar, const int* bcon, int* gs0, int* gs3) {
  int gid = blockIdx.x * 256 + threadIdx.x;
  const int N0 = 100000, N3 = 80000;
  if (gid < N0) {
    int i = gid;
    int b = bvar[i];
    int bp = i ? bvar[i - 1] : -1;
    for (int g = bp + 1; g <= b; ++g) gs0[g] = i;
    if (i == N0 - 1) for (int g = b + 1; g <= 64; ++g) gs0[g] = N0;
  } else if (gid < N0 + N3) {
    int i = gid - N0;
    int b = bcon[i];
    int bp = i ? bcon[i - 1] : -1;
    for (int g = bp + 1; g <= b; ++g) gs3[g] = i;
    if (i == N3 - 1) for (int g = b + 1; g <= 64; ++g) gs3[g] = N3;
  }
}

__global__ __launch_bounds__(256) void k_pool2(const float* xfin, const int* gs0, const int* gs3,
                                               float* partial) {
  __shared__ float4 sdv[256];
  int b = blockIdx.x;
  int sp = b >> 7;
  int rem = b & 127;
  int g = rem >> 1;
  int t = rem & 1;                    // 0 -> type0, 1 -> type3
  const int* gs = t ? gs3 : gs0;
  int xbase = t ? 170000 : 0;
  int lo = gs[g], hi = gs[g + 1];
  int len = hi - lo;
  int r0 = lo + (len * sp) / 8;
  int r1 = lo + (len * (sp + 1)) / 8;
  int tid = threadIdx.x;
  int rp = tid >> 4;                  // 16 rows in flight
  int cq = tid & 15;                  // column quad
  float4 acc = make_float4(0.f, 0.f, 0.f, 0.f);
  for (int row = r0 + rp; row < r1; row += 16) {
    float4 v = ((const float4*)xfin)[(size_t)(xbase + row) * 16 + cq];
    acc.x += fmaxf(v.x, 0.f); acc.y += fmaxf(v.y, 0.f);
    acc.z += fmaxf(v.z, 0.f); acc.w += fmaxf(v.w, 0.f);
  }
  sdv[tid] = acc;
  __syncthreads();
  for (int o = 128; o >= 16; o >>= 1) {
    if (tid < o) {
      float4 a = sdv[tid], c = sdv[tid + o];
      a.x += c.x; a.y += c.y; a.z += c.z; a.w += c.w;
      sdv[tid] = a;
    }
    __syncthreads();
  }
  if (tid < 16) ((float4*)&partial[(size_t)b * 64])[tid] = sdv[tid];
}

__global__ void k_poolred2(const float* partial, float* pool) {
  int g = blockIdx.x >> 1;
  int t = blockIdx.x & 1;
  int col = threadIdx.x;
  float s = 0.f;
#pragma unroll
  for (int sp = 0; sp < 8; ++sp)
    s += partial[(size_t)(((sp << 7) | (g << 1) | t)) * 64 + col];
  pool[(t ? 4096 : 0) + g * 64 + col] = s;
}

__global__ void k_final(const float* pool, const int* gs0, const int* gs3,
                        const float* lin_w, const float* lin_b, float* out) {
  int k = threadIdx.x;          // 128 = 64 graphs x 2 outputs
  int g = k >> 1, o = k & 1;
  float c0 = fmaxf((float)(gs0[g + 1] - gs0[g]), 1.f);
  float c3 = fmaxf((float)(gs3[g + 1] - gs3[g]), 1.f);
  float acc = lin_b[o];
  for (int i = 0; i < 64; ++i) {
    acc += (pool[g * 64 + i] / c0) * lin_w[o * 128 + i];
    acc += (pool[4096 + g * 64 + i] / c3) * lin_w[o * 128 + 64 + i];
  }
  out[g * 2 + o] = acc;
}

__global__ void k_bail(float* out) {
  if (threadIdx.x < 128) out[threadIdx.x] = 0.f;
}

// ---------------- host launch ----------------
extern "C" void kernel_launch(void* const* d_in, const int* in_sizes, int n_in,
                              void* d_out, int out_size, void* d_ws, size_t ws_size,
                              hipStream_t stream) {
  (void)in_sizes; (void)n_in; (void)out_size;
  // ---- workspace layout (float units) ----
  const size_t O_XA   = 0;            // 16,000,000 (layer-1 out; layer-2 writes types 0/3 in place)
  const size_t O_HS   = 16000000;     // 21,120,000 (bf16 hs: 660k rows x 64 x 2B)
                                      //   aliases (each dead before hs is written that layer):
                                      //   CSR arrays (l1 pre-gemm); sscr fp32[2.7M] during k_soft
  const size_t O_ALS  = 37120000;     //    660,000
  const size_t O_ALD  = 37780000;     //    660,000
  const size_t O_ESC  = 38440000;     //  1,350,000 (fp16[2.7M] per-edge alpha)
  const size_t O_WV   = 39790000;     //      2,304
  const size_t O_BS   = 39792304;     //        512
  const size_t O_RP   = 39792816;     //    660,016 (int; 660,001 used)
  const size_t O_ASX  = 40452832;     //  2,700,000 (int)
  const size_t O_GS   = 43152832;     //        256 (int; gs0[65]+gs3[65])
  const size_t O_PART = 43153088;     //     65,536 (1024 blocks x 64)
  const size_t O_POOL = 43218624;     //      8,192
  const size_t NEED   = 43226816;     // floats (~172.9 MB; 177.6 MB proven available)

  if (ws_size < NEED * 4) {           // graceful, deterministic bail (diagnostic)
    k_bail<<<1, 128, 0, stream>>>((float*)d_out);
    return;
  }

  const float* x0 = (const float*)d_in[0];
  const float* x1 = (const float*)d_in[1];
  const float* x2 = (const float*)d_in[2];
  const float* x3 = (const float*)d_in[3];
  const float* Wsrc = (const float*)d_in[4];
  const float* Wdst = (const float*)d_in[5];
  const float* asrc = (const float*)d_in[6];
  const float* adst = (const float*)d_in[7];
  const float* bias = (const float*)d_in[8];
  const float* lin_w = (const float*)d_in[9];
  const float* lin_b = (const float*)d_in[10];
  EdgePtrs Eg;
  for (int r = 0; r < 9; ++r) {
    Eg.s[r] = (const int*)d_in[11 + 2 * r];
    Eg.d[r] = (const int*)d_in[12 + 2 * r];
  }
  const int* bvar = (const int*)d_in[29];
  const int* bcon = (const int*)d_in[30];

  float* ws = (float*)d_ws;
  float* xA   = ws + O_XA;
  __hip_bfloat16* hs = (__hip_bfloat16*)(ws + O_HS);
  int* bh     = (int*)(ws + O_HS);                 // alias, dead before gemms
  int* pairs  = bh + (size_t)NBLK * NBUCK;         // alias (NBLK*NBUCK = 3,406,977)
  int* gbh    = pairs + 2700000;                   // alias
  int* boff   = gbh + 2584;                        // alias
  int* csum   = boff + 2592;                       // alias (KCH*NBUCK = 51,660)
  float* sscr = ws + O_HS;                         // alias: score scratch during k_soft
  float* als  = ws + O_ALS;
  float* ald  = ws + O_ALD;
  _Float16* esc = (_Float16*)(ws + O_ESC);
  float* wv   = ws + O_WV;
  float* bsum = ws + O_BS;
  int* rowptr = (int*)(ws + O_RP);
  int* asx    = (int*)(ws + O_ASX);
  int* gs0    = (int*)(ws + O_GS);
  int* gs3    = gs0 + 65;
  float* partial = ws + O_PART;
  float* pool = ws + O_POOL;

  const int h_NS[4]   = {100000, 20000, 50000, 80000};
  const int h_SRC[9]  = {0,0,0,2,3,1,2,3,3};
  const int h_XOFF[4] = {0,100000,120000,170000};

  k_setup<<<37, 64, 0, stream>>>(Wsrc, Wdst, asrc, adst, bias, wv, bsum);

  // CSR build: deterministic block-private bucket sort, zero global atomics
  k_bhist2<<<NBLK, 256, 0, stream>>>(Eg, bh);
  k_cs1<<<KCH * 11, 256, 0, stream>>>(bh, csum);
  k_cs2<<<11, 256, 0, stream>>>(csum, gbh);
  k_cs3<<<KCH * 11, 256, 0, stream>>>(bh, csum);
  k_bscan<<<1, 1024, 0, stream>>>(gbh, boff);
  k_bin2<<<NBLK, 256, 0, stream>>>(Eg, bh, boff, pairs);
  k_bsort<<<NBUCK, 256, 0, stream>>>(pairs, boff, rowptr, asx);
  k_gbound<<<(180000 + 255) / 256, 256, 0, stream>>>(bvar, bcon, gs0, gs3);

  for (int l = 0; l < 2; ++l) {
    const float* xin[4];
    if (l == 0) { xin[0] = x0; xin[1] = x1; xin[2] = x2; xin[3] = x3; }
    else {
      for (int t = 0; t < 4; ++t) xin[t] = xA + (size_t)h_XOFF[t] * 64;
    }
    int act = (l > 0);
    int relmask = l ? 0x0FC : 0x1FF;   // layer 2: dst types 1,2 unused -> skip r0,r1,r8

    AlphaP AP;
    AP.x0 = xin[0]; AP.x1 = xin[1]; AP.x2 = xin[2]; AP.x3 = xin[3];
    AP.als = als; AP.ald = ald;
    AP.wvs = wv + l * 576; AP.wvd = wv + 1152 + l * 576;
    AP.act = act; AP.smask = relmask; AP.dmask = relmask;
    k_alphas<<<(TOTROWS + 255) / 256, 256, 0, stream>>>(AP);

    SoftP SP;
    SP.als = als; SP.ald = ald; SP.rowptr = rowptr; SP.asx = asx;
    SP.sscr = sscr; SP.esc = esc;
    SP.segLo = l ? 70000 : 0;                 // layer 2: segs of r2..r7 are contiguous
    SP.segN  = l ? 540000 : TOTSEG;
    k_soft<<<(SP.segN + 255) / 256, 256, 0, stream>>>(SP);

    // ONE merged MFMA-GEMM launch for all active relations of this layer
    GemmAllP G;
    G.x0 = xin[0]; G.x1 = xin[1]; G.x2 = xin[2]; G.x3 = xin[3];
    G.Wl = Wsrc + (size_t)l * 9 * 4096;
    G.hs = hs; G.act = act;
    int nrel = 0, cum = 0;
    for (int r = 0; r < 9; ++r) {
      if (!((relmask >> r) & 1)) continue;
      G.rel[nrel] = r;
      G.tbase[nrel] = cum;
      cum += (h_NS[h_SRC[r]] + 63) / 64;
      ++nrel;
    }
    G.nrel = nrel; G.tbase[nrel] = cum;
    k_gemma<<<cum, 256, 0, stream>>>(G);

    // ONE merged gather launch for all active dst types of this layer
    GatherAllP A;
    A.hs = hs; A.esc = esc;
    A.rowptr = rowptr; A.asx = asx;
    A.xA = xA;                                   // layer 2 writes xA in place (xA dead post-gemm)
    A.bsum = bsum + l * 256;
    int nt = 0, bcum = 0;
    for (int t = 0; t < 4; ++t) {
      if (l == 1 && (t == 1 || t == 2)) continue;   // dead outputs in layer 2
      A.typ[nt] = t;
      A.tbase[nt] = bcum;
      bcum += (h_NS[t] + 7) / 8;
      ++nt;
    }
    A.ntypes = nt; A.tbase[nt] = bcum;
    k_gatherall<<<bcum, 256, 0, stream>>>(A);
  }

  k_pool2<<<1024, 256, 0, stream>>>(xA, gs0, gs3, partial);
  k_poolred2<<<128, 64, 0, stream>>>(partial, pool);
  k_final<<<1, 128, 0, stream>>>(pool, gs0, gs3, lin_w, lin_b, (float*)d_out);
}